// Round 9
// baseline (634.227 us; speedup 1.0000x reference)
//
#include <hip/hip_runtime.h>
#include <hip/hip_bf16.h>
#include <cstdint>

typedef unsigned short u16;
typedef __attribute__((ext_vector_type(8))) short short8;
typedef __attribute__((ext_vector_type(4))) float floatx4;
typedef __attribute__((ext_vector_type(4))) int intx4;

#define PA_TOTAL 13696   // sum of per-level pixel counts, each padded to 128
#define CCH 256
#define KTOT 2304        // 9 taps * 256 ic

struct Tables {
  int H[5], W[5], P[5], base[5], tile0[5];
  int lb[5], bb[5], cb[5];   // d_out offsets: logits, bbox, centerness per level
};
struct FeatPtrs { const float* f[5]; };
struct ConvArgs {
  const u16* X[2];      // per-tower input activations
  const u16* Wt[2];     // per-tower weight matrices for this stage
  u16* outB[2];         // per-tower conv output (bf16 NHWC)
  float* stats;         // [tower][ (b*5+lvl)*32+g ][2]  -> tower stride 640 floats
  float* dout;
  const float* biasCls; const float* biasCtr; const float* biasBox; const float* scales;
};
struct ReorderArgs {
  const float* cls_w; const float* box_w; const float* pcls_w; const float* ctr_w; const float* pbox_w;
  u16* wrCls; u16* wrBox; u16* wrPCls; u16* wrPBox;
};

__device__ __forceinline__ u16 f2bf(float f) {
  union { float f; unsigned u; } v; v.f = f;
  unsigned r = v.u + 0x7fffu + ((v.u >> 16) & 1u);   // RNE
  return (u16)(r >> 16);
}
__device__ __forceinline__ float bf2f(u16 h) {
  union { unsigned u; float f; } v; v.u = ((unsigned)h) << 16;
  return v.f;
}

// async global->LDS: 16B per lane, dest = wave-uniform base + lane*16.
__device__ __forceinline__ void gload16(const void* g, void* l) {
  __builtin_amdgcn_global_load_lds(
      (const __attribute__((address_space(1))) void*)g,
      (__attribute__((address_space(3))) void*)l, 16, 0, 0);
}

// ---- ALL weight reordering in ONE launch (R8 consolidation, kept).
// rows 0..1023: cls tower; 1024..2047: box tower; 2048..2067: cls_pred;
// 2068: ctr_pred (row 20 of pred-cls matrix); 2069..2072: box_pred;
// 2073..2083: zero pred-cls rows 21..31; 2084..2111: zero pred-box rows 4..31.
__global__ void reorder_all(ReorderArgs ra) {
  __shared__ float row[KTOT];
  const int r = blockIdx.x;
  const float* s;
  u16* o;
  if (r < 1024)      { s = ra.cls_w  + (size_t)r * KTOT;          o = ra.wrCls  + (size_t)r * KTOT; }
  else if (r < 2048) { int q = r - 1024; s = ra.box_w  + (size_t)q * KTOT; o = ra.wrBox  + (size_t)q * KTOT; }
  else if (r < 2068) { int q = r - 2048; s = ra.pcls_w + (size_t)q * KTOT; o = ra.wrPCls + (size_t)q * KTOT; }
  else if (r == 2068){ s = ra.ctr_w;                               o = ra.wrPCls + (size_t)20 * KTOT; }
  else if (r < 2073) { int q = r - 2069; s = ra.pbox_w + (size_t)q * KTOT; o = ra.wrPBox + (size_t)q * KTOT; }
  else if (r < 2084) {
    u16* oz = ra.wrPCls + (size_t)(21 + (r - 2073)) * KTOT;
#pragma unroll
    for (int j = 0; j < 9; ++j) oz[threadIdx.x + j * 256] = 0;
    return;
  } else {
    u16* oz = ra.wrPBox + (size_t)(4 + (r - 2084)) * KTOT;
#pragma unroll
    for (int j = 0; j < 9; ++j) oz[threadIdx.x + j * 256] = 0;
    return;
  }
#pragma unroll
  for (int j = 0; j < 9; ++j) row[threadIdx.x + j * 256] = s[threadIdx.x + j * 256];
  __syncthreads();
#pragma unroll
  for (int j = 0; j < 9; ++j) {
    int k = threadIdx.x + j * 256;
    o[k] = f2bf(row[(k & 255) * 9 + (k >> 8)]);
  }
}

// ---- inputs NCHW f32 -> NHWC bf16, 32x32 LDS transpose (coalesced both sides)
// grid: (PA_TOTAL/32, 8, 2)  block 256. Pixel-padding rows written as ZERO
// (they are the conv staging's halo redirect target).
__global__ void convert_inputs(FeatPtrs fp, u16* __restrict__ out, Tables tb) {
  __shared__ float tile[32][33];
  const int pt = blockIdx.x, c32 = blockIdx.y, b = blockIdx.z;
  const int p0 = pt * 32;
  int lvl = 0;
#pragma unroll
  for (int i = 1; i < 5; ++i) if (p0 >= tb.base[i]) lvl = i;
  const int P = tb.P[lvl];
  const int pl0 = p0 - tb.base[lvl];
  const int r = threadIdx.x >> 5, col = threadIdx.x & 31;
  const float* src = fp.f[lvl] + ((size_t)b * CCH + c32 * 32) * P;
#pragma unroll
  for (int i = 0; i < 4; ++i) {
    int crow = r + i * 8;
    int pl = pl0 + col;
    tile[crow][col] = (pl < P) ? src[(size_t)crow * P + pl] : 0.f;
  }
  __syncthreads();
#pragma unroll
  for (int i = 0; i < 4; ++i) {
    int px = r + i * 8;
    out[((size_t)b * PA_TOTAL + p0 + px) * CCH + c32 * 32 + col] = f2bf(tile[col][px]);
  }
}

// ---- implicit-GEMM conv3x3 SAME, bf16 MFMA 16x16x32, BK=64, 128-px tiles.
// THE R7 STRUCTURE (numerically hardware-verified: R7 passed) WITH THE
// REGISTER CAP REMOVED. Both X and W staged via global_load_lds into ONE
// contiguous LDS symbol (X at [0,16K), W after), single-buffered; XOR swizzle
// pre-folded into per-lane GLOBAL source; per step:
//   __syncthreads -> issue NI W-gloads + 4 X-gloads -> vmcnt(0)+s_barrier -> MFMA.
// Mechanism (R8 model): step wall (~9100cy) is 2.4x the busiest pipe; the
// critical path is LDS-queue contention (96 wave-LDS-instr/step across 3.34
// co-resident blocks) + barrier coupling. Deleting all 32 ds_writes/step
// (-33% LDS instr) and 32 staging VGPRs attacks exactly that. R7's only
// failure was __launch_bounds__(256,5) forcing VGPR=48 -> accumulator spill
// (157MB FETCH). Plain bounds -> natural ~90-110 VGPR, no spill, same
// 4-waves/SIMD occupancy as the 120-VGPR baseline.
// Halo-invalid lanes redirect their source OFFSET to the level's zero
// pixel-padding rows (bufIn zeroed by convert_inputs, bufAct pads zeroed by
// gn_norm) - load always issues, LDS slots get real zeros.
// MODE 0: 128x128 tile, tower stage -> bf16 NHWC + fused GN stats. grid (107,2,4).
// MODE 1: 32x128 tile (21/4 real oc rows), pred convs -> d_out NCHW. grid (108,2,2).
template <int MODE>
__global__ __launch_bounds__(256) void conv_mfma(ConvArgs a, Tables tb) {
  constexpr int NI = (MODE == 0) ? 4 : 1;     // A-frag rows per wave
  constexpr int WROWS = (MODE == 0) ? 128 : 32;
  const int L = blockIdx.x + (MODE == 0 ? 107 : 108) * (blockIdx.y + 2 * blockIdx.z);
  const int xcd = L & 7, slot = L >> 3;
  int tower, mt, b, t;
  if (MODE == 0) {
    tower = xcd >> 2; mt = (xcd >> 1) & 1; b = xcd & 1; t = slot;
  } else {
    tower = xcd >> 2; mt = 0; b = (xcd >> 1) & 1; t = slot * 2 + (xcd & 1);
    if (t >= 107) return;
  }
  int lvl = 0;
#pragma unroll
  for (int i = 1; i < 5; ++i) if (t >= tb.tile0[i]) lvl = i;
  const int H = tb.H[lvl], W = tb.W[lvl], P = tb.P[lvl], base = tb.base[lvl];
  const int n0 = (t - tb.tile0[lvl]) * 128;

  const int tid = threadIdx.x;
  const int lane = tid & 63, wv = tid >> 6;
  const int wm = wv >> 1, wn = wv & 1;

  // ONE contiguous LDS block: X tile at [0, 16384) bytes, W tile after it.
  __shared__ u16 ldsAll[128 * 64 + WROWS * 64];
  u16* ldsX = ldsAll;                 // [px][64 ic] swizzled, 16KB
  u16* ldsW = ldsAll + 128 * 64;      // [oc][64 k] swizzled

  const u16* X = a.X[tower];
  const u16* Wt = a.Wt[tower];
  const char* Xb = (const char*)(X + ((size_t)b * PA_TOTAL + base) * CCH);
  const char* Wb = (const char*)(Wt + (size_t)(MODE == 0 ? mt * 128 : 0) * KTOT);

  // staging geometry: chunk ci = (t4*4+wv)*64 + lane -> row=ci>>3, col=lane&7;
  // slot (row,col) holds k-chunk q' = col ^ (row&7) -> swizzle pre-folded into
  // the per-lane GLOBAL byte offset qsw2; LDS dest is linear lane*16.
  const int qsw2 = ((lane & 7) ^ (lane >> 3)) * 16;   // byte offset of fetched chunk
  int xoffG[4];                      // per-lane global byte offsets (row term)
  unsigned mask9[4];
  int xlds[4];                       // wave-uniform LDS byte bases
#pragma unroll
  for (int t4 = 0; t4 < 4; ++t4) {
    int row = (t4 * 4 + wv) * 8 + (lane >> 3);
    int prow = n0 + row;
    int rr = prow / W, cc = prow - rr * W;
    unsigned m = 0;
#pragma unroll
    for (int tap = 0; tap < 9; ++tap) {
      const int dh = tap / 3 - 1, dw = tap % 3 - 1;
      bool v = ((unsigned)(rr + dh) < (unsigned)H) & ((unsigned)(cc + dw) < (unsigned)W);
      m |= ((unsigned)v) << tap;
    }
    mask9[t4] = m;
    xoffG[t4] = prow * (CCH * 2) + qsw2;
    xlds[t4] = (t4 * 4 + wv) * 1024;
  }
  const int padoff = P * (CCH * 2) + qsw2;   // zero pixel-padding row (halo target)
  int woffG[NI];
  int wlds[NI];                      // wave-uniform byte base within W region
#pragma unroll
  for (int e = 0; e < NI; ++e) {
    int wrow = (MODE == 0) ? ((e * 4 + wv) * 8 + (lane >> 3)) : (wv * 8 + (lane >> 3));
    woffG[e] = wrow * (KTOT * 2) + qsw2;
    wlds[e] = 16384 + ((MODE == 0) ? ((e * 4 + wv) * 1024) : (wv * 1024));
  }

  // fragment LDS offsets (u16), reader swizzle col = kq ^ (row&7);
  // h=1 offsets are h=0 ^ 32 elems (bit-2 of kq scaled by 8; no carry).
  const int arow = lane & 15, rsw = lane & 7, kq0 = lane >> 4;
  const int csw0 = (kq0 ^ rsw) * 8;
  int aoff[NI], boff[4];
#pragma unroll
  for (int i = 0; i < NI; ++i) {
    int rowb = (MODE == 0) ? (wm * 64 + i * 16) : (wm * 16);
    aoff[i] = (rowb + arow) * 64 + csw0;
  }
#pragma unroll
  for (int i = 0; i < 4; ++i) boff[i] = (wn * 64 + i * 16 + arow) * 64 + csw0;

  floatx4 acc[NI][4];
#pragma unroll
  for (int i = 0; i < NI; ++i)
#pragma unroll
    for (int j = 0; j < 4; ++j) acc[i][j] = (floatx4)0.f;

  // K-loop: icb outer, taps inner (unrolled). Uniform step body; all staging
  // is async DMA, no staging registers, no ds_writes.
#pragma unroll 1
  for (int icb = 0; icb < 4; ++icb) {
#pragma unroll
    for (int tap = 0; tap < 9; ++tap) {
      __syncthreads();   // all waves done reading LDS of previous step
      const int ko = (tap * 256 + icb * 64) * 2;                 // W byte off, uniform
      const int dh = tap / 3 - 1, dw = tap % 3 - 1;
      const int doff = (dh * W + dw) * (CCH * 2) + icb * 128;    // X byte off, uniform
#pragma unroll
      for (int e = 0; e < NI; ++e)
        gload16(Wb + woffG[e] + ko, (char*)ldsAll + wlds[e]);
#pragma unroll
      for (int t4 = 0; t4 < 4; ++t4) {
        const int off = ((mask9[t4] >> tap) & 1u) ? (xoffG[t4] + doff) : padoff;
        gload16(Xb + off, (char*)ldsAll + xlds[t4]);
      }
      // all 4+NI gloads must land block-wide before MFMA reads LDS
      asm volatile("s_waitcnt vmcnt(0) lgkmcnt(0)\n\ts_barrier" ::: "memory");
      __builtin_amdgcn_s_setprio(1);
#pragma unroll
      for (int h = 0; h < 2; ++h) {
        const int hx = h * 32;
        short8 af[NI], bv[4];
#pragma unroll
        for (int i = 0; i < NI; ++i) af[i] = *(const short8*)(ldsW + (aoff[i] ^ hx));
#pragma unroll
        for (int j = 0; j < 4; ++j) bv[j] = *(const short8*)(ldsX + (boff[j] ^ hx));
#pragma unroll
        for (int i = 0; i < NI; ++i)
#pragma unroll
          for (int j = 0; j < 4; ++j)
            acc[i][j] = __builtin_amdgcn_mfma_f32_16x16x32_bf16(af[i], bv[j], acc[i][j], 0, 0, 0);
      }
      __builtin_amdgcn_s_setprio(0);
    }
  }

  // epilogue; D[m=(lane>>4)*4+r][n=lane&15]
  const int quad = lane >> 4, col = lane & 15;
  if (MODE == 0) {
    u16* convB = a.outB[tower];
    float s[4] = {0.f, 0.f, 0.f, 0.f}, ss[4] = {0.f, 0.f, 0.f, 0.f};
#pragma unroll
    for (int j = 0; j < 4; ++j) {
      int pl = n0 + wn * 64 + j * 16 + col;
      bool valid = pl < P;
      u16* dst = convB + ((size_t)b * PA_TOTAL + base + pl) * CCH + mt * 128 + wm * 64 + quad * 4;
#pragma unroll
      for (int i = 0; i < 4; ++i) {
        ushort4 hv;
#pragma unroll
        for (int r = 0; r < 4; ++r) {
          u16 hh = f2bf(acc[i][j][r]);
          ((u16*)&hv)[r] = hh;
          float vr = bf2f(hh);                    // accumulate ROUNDED value -> GN self-consistent
          if (valid) { s[i] += vr; ss[i] += vr * vr; }
        }
        if (valid) *(ushort4*)(dst + i * 16) = hv;
      }
    }
#pragma unroll
    for (int i = 0; i < 4; ++i) {
#pragma unroll
      for (int off = 16; off >= 1; off >>= 1) {
        s[i] += __shfl_down(s[i], off, 64);
        ss[i] += __shfl_down(ss[i], off, 64);
      }
    }
    if ((lane & 31) == 0) {
      int half = lane >> 5;
#pragma unroll
      for (int i = 0; i < 4; ++i) {
        float* st = a.stats + tower * 640 +
                    ((size_t)((b * 5 + lvl) * 32 + mt * 16 + wm * 8 + i * 2 + half)) * 2;
        atomicAdd(st, s[i]);
        atomicAdd(st + 1, ss[i]);
      }
    }
  } else {
    float* dout = a.dout;
    if (tower == 0) {
#pragma unroll
      for (int j = 0; j < 4; ++j) {
        int pl = n0 + wn * 64 + j * 16 + col;
        if (pl >= P) continue;
        int ocb = wm * 16 + quad * 4;
#pragma unroll
        for (int r = 0; r < 4; ++r) {
          int oc = ocb + r;
          float v = acc[0][j][r];
          if (oc < 20)       dout[tb.lb[lvl] + ((size_t)b * 20 + oc) * P + pl] = v + a.biasCls[oc];
          else if (oc == 20) dout[tb.cb[lvl] + (size_t)b * P + pl] = v + a.biasCtr[0];
        }
      }
    } else {
      float sc = a.scales[lvl];
#pragma unroll
      for (int j = 0; j < 4; ++j) {
        int pl = n0 + wn * 64 + j * 16 + col;
        if (pl >= P) continue;
        int ocb = wm * 16 + quad * 4;
#pragma unroll
        for (int r = 0; r < 4; ++r) {
          int oc = ocb + r;
          if (oc < 4)
            dout[tb.bb[lvl] + ((size_t)b * 4 + oc) * P + pl] = expf((acc[0][j][r] + a.biasBox[oc]) * sc);
        }
      }
    }
  }
}

// ---- GroupNorm pass 2: normalize + affine + ReLU, bf16 -> bf16, coalesced; both towers.
// grid (3424, 2): y = tower. Pixel-padding rows ZEROED (conv halo redirect target).
__global__ void gn_norm(const u16* __restrict__ c0, const u16* __restrict__ c1,
                        const float* __restrict__ stats,
                        const float* __restrict__ g0, const float* __restrict__ b0,
                        const float* __restrict__ g1, const float* __restrict__ b1,
                        u16* __restrict__ a0, u16* __restrict__ a1, Tables tb) {
  const int tower = blockIdx.y;
  const u16* convB = tower ? c1 : c0;
  const float* gamma = tower ? g1 : g0;
  const float* beta = tower ? b1 : b0;
  u16* act = tower ? a1 : a0;
  int idx = blockIdx.x * 256 + threadIdx.x;
  int c8 = idx & 31;                 // == group index
  int rest = idx >> 5;
  int p = rest % PA_TOTAL;
  int b = rest / PA_TOTAL;
  int lvl = 0;
#pragma unroll
  for (int i = 1; i < 5; ++i) if (p >= tb.base[i]) lvl = i;
  if (p - tb.base[lvl] >= tb.P[lvl]) {
    short8 z = (short8)(short)0;
    *(short8*)(act + ((size_t)b * PA_TOTAL + p) * CCH + c8 * 8) = z;
    return;
  }
  const float* st = stats + tower * 640 + ((size_t)((b * 5 + lvl) * 32 + c8)) * 2;
  float cnt = 8.f * (float)tb.P[lvl];
  float mean = st[0] / cnt;
  float var = st[1] / cnt - mean * mean;
  float inv = rsqrtf(var + 1e-5f);
  const short8 x = *(const short8*)(convB + ((size_t)b * PA_TOTAL + p) * CCH + c8 * 8);
  short8 o;
#pragma unroll
  for (int j = 0; j < 8; ++j) {
    float v = bf2f((u16)x[j]);
    float y = (v - mean) * inv * gamma[c8 * 8 + j] + beta[c8 * 8 + j];
    y = fmaxf(y, 0.f);
    o[j] = (short)f2bf(y);
  }
  *(short8*)(act + ((size_t)b * PA_TOTAL + p) * CCH + c8 * 8) = o;
}

extern "C" void kernel_launch(void* const* d_in, const int* in_sizes, int n_in,
                              void* d_out, int out_size, void* d_ws, size_t ws_size,
                              hipStream_t stream) {
  const float* feat[5];
  for (int i = 0; i < 5; ++i) feat[i] = (const float*)d_in[i];
  const float* cls_tw_w  = (const float*)d_in[5];
  const float* cls_tw_g  = (const float*)d_in[6];
  const float* cls_tw_b  = (const float*)d_in[7];
  const float* box_tw_w  = (const float*)d_in[8];
  const float* box_tw_g  = (const float*)d_in[9];
  const float* box_tw_b  = (const float*)d_in[10];
  const float* cls_pred_w = (const float*)d_in[11];
  const float* cls_pred_b = (const float*)d_in[12];
  const float* box_pred_w = (const float*)d_in[13];
  const float* box_pred_b = (const float*)d_in[14];
  const float* ctr_pred_w = (const float*)d_in[15];
  const float* ctr_pred_b = (const float*)d_in[16];
  const float* scales     = (const float*)d_in[17];
  float* out = (float*)d_out;

  char* ws = (char*)d_ws;
  float* statsAll = (float*)(ws);                    // 4 stages x 1280 floats = 20480 B
  u16*   WrCls  = (u16*)(ws + 24576);                // 1024 x 2304 bf16
  u16*   WrBox  = (u16*)(ws + 24576 + 4718592);
  u16*   WrPCls = (u16*)(ws + 24576 + 2 * 4718592);              // 32 x 2304 (21 used)
  u16*   WrPBox = (u16*)(ws + 24576 + 2 * 4718592 + 147456);     // 32 x 2304 (4 used)
  u16*   bufIn   = (u16*)(ws + 10625024);
  u16*   bufAct0 = (u16*)(ws + 10625024 + 1 * (size_t)14024704);
  u16*   bufAct1 = (u16*)(ws + 10625024 + 2 * (size_t)14024704);
  u16*   bufCv0  = (u16*)(ws + 10625024 + 3 * (size_t)14024704);
  u16*   bufCv1  = (u16*)(ws + 10625024 + 4 * (size_t)14024704);

  Tables tb = { {100,50,25,13,7}, {100,50,25,13,7}, {10000,2500,625,169,49},
                {0,10112,12672,13312,13568}, {0,79,99,104,106},
                {0,400000,500000,525000,531760},
                {533720,613720,633720,638720,640072},
                {640464,660464,665464,666714,667052} };

  // one upfront memset for all 4 stages' stats
  hipMemsetAsync(statsAll, 0, 20480, stream);

  ReorderArgs ra = { cls_tw_w, box_tw_w, cls_pred_w, ctr_pred_w, box_pred_w,
                     WrCls, WrBox, WrPCls, WrPBox };
  reorder_all<<<2112, 256, 0, stream>>>(ra);

  FeatPtrs fp = {{feat[0], feat[1], feat[2], feat[3], feat[4]}};
  convert_inputs<<<dim3(PA_TOTAL / 32, 8, 2), 256, 0, stream>>>(fp, bufIn, tb);

  ConvArgs a;
  a.dout = out;
  a.biasCls = cls_pred_b; a.biasCtr = ctr_pred_b; a.biasBox = box_pred_b; a.scales = scales;
  a.outB[0] = bufCv0; a.outB[1] = bufCv1;

  for (int s = 0; s < 4; ++s) {
    a.X[0] = (s == 0) ? bufIn : bufAct0;
    a.X[1] = (s == 0) ? bufIn : bufAct1;
    a.Wt[0] = WrCls + (size_t)s * 256 * KTOT;
    a.Wt[1] = WrBox + (size_t)s * 256 * KTOT;
    a.stats = statsAll + (size_t)s * 1280;
    conv_mfma<0><<<dim3(107, 2, 4), 256, 0, stream>>>(a, tb);
    gn_norm<<<dim3(3424, 2), 256, 0, stream>>>(bufCv0, bufCv1, a.stats,
                                               cls_tw_g + s * 256, cls_tw_b + s * 256,
                                               box_tw_g + s * 256, box_tw_b + s * 256,
                                               bufAct0, bufAct1, tb);
  }
  a.X[0] = bufAct0; a.X[1] = bufAct1;
  a.Wt[0] = WrPCls; a.Wt[1] = WrPBox;
  conv_mfma<1><<<dim3(108, 2, 2), 256, 0, stream>>>(a, tb);
}